// Round 2
// baseline (303.846 us; speedup 1.0000x reference)
//
#include <hip/hip_runtime.h>

// DepthDeformConvPack on MI355X — round 6: move the bilinear gather into LDS.
// r5 post-mortem: doubling occupancy (21->43%) did NOT help (151us, VALU/MFMA
// both fell) -> saturated shared throughput, not latency. The culprit is L1
// request throughput: 75.5M scattered lane-loads (~1 distinct 64B line each,
// offsets sigma~2.7 rows) / ~1 line/cy/CU = ~120us floor. FETCH=15.8MB shows
// L2 absorbs everything; the cost is pure L1 tag processing.
// Changes (K3 only; K0/K1/K2 untouched):
//   (a) x row-strips (18 rows x 256B) staged per-channel into a 9-slot LDS
//       ring via coalesced global_load_lds; bilinear gather via ds_read
//       (LDS is scatter-native: random addrs ~2-4-way conflicts only).
//       Rare fallback to global for |dy|>8 (<0.3%/lane).
//   (b) loop: {stage next 7-8 channels || af+MFMA} -> barrier (drains stage)
//       -> gather->Bs -> barrier. Bs single-buffered (9KB).
//       LDS total 60.75KB. Grid back to 256 (BN=64, r4's faster shape).

typedef __bf16 bf16x8 __attribute__((ext_vector_type(8)));
typedef float f32x4 __attribute__((ext_vector_type(4)));
typedef float float2_u __attribute__((ext_vector_type(2), aligned(4)));

__device__ __forceinline__ unsigned short f2bf(float f) {
  unsigned b = __float_as_uint(f);
  return (unsigned short)((b + 0x7fffu + ((b >> 16) & 1u)) >> 16);
}

// ---------------------------------------------------------------------------
// K0: weight fp32 -> bf16, natural layout (k = c*9+tap is already channel-major)
// ---------------------------------------------------------------------------
__global__ __launch_bounds__(256) void k_prep_weight(
    const float* __restrict__ w, unsigned short* __restrict__ wbf)
{
  const int i = blockIdx.x * 256 + threadIdx.x;   // grid 2304 -> 589824
  wbf[i] = f2bf(w[i]);
}

// ---------------------------------------------------------------------------
// K1: offset conv. grid = 4 ch-segments x (n,ho)=256 -> 1024 blocks, 256 thr.
// ---------------------------------------------------------------------------
__global__ __launch_bounds__(256) void k_offset_conv(
    const float* __restrict__ x, const float* __restrict__ depth,
    const float* __restrict__ off_w, const float* __restrict__ off_b,
    float* __restrict__ offs)
{
  const int seg = blockIdx.x >> 8;        // 0..3
  const int nh  = blockIdx.x & 255;
  const int n = nh >> 6, ho = nh & 63;
  const int tid = threadIdx.x;
  const int lane = tid & 63;              // == wo
  const int wave = tid >> 6;

  float acc[18];
#pragma unroll
  for (int i = 0; i < 18; ++i) acc[i] = 0.f;

  const int c0 = __builtin_amdgcn_readfirstlane(seg * 80 + wave * 20);

  for (int ci = 0; ci < 20; ++ci) {
    const int c = c0 + ci;
    const float* p = (c < 256) ? (x + (((n << 8) + c) << 12))
                               : (depth + (((n << 6) + (c - 256)) << 12));
    const float v0 = (ho > 0)  ? p[((ho - 1) << 6) + lane] : 0.f;
    const float v1 =             p[( ho      << 6) + lane];
    const float v2 = (ho < 63) ? p[((ho + 1) << 6) + lane] : 0.f;

    float v[9];
#pragma unroll
    for (int ky = 0; ky < 3; ++ky) {
      const float r = (ky == 0) ? v0 : ((ky == 1) ? v1 : v2);
#pragma unroll
      for (int kx = 0; kx < 3; ++kx) {
        const int src = lane + kx - 1;
        const float s = __shfl(r, src & 63);
        v[ky * 3 + kx] = (src >= 0 && src < 64) ? s : 0.f;
      }
    }
    const float* wp = off_w + c * 9;   // wave-uniform address
#pragma unroll
    for (int co = 0; co < 18; ++co) {
      const float* w = wp + co * 2880;
#pragma unroll
      for (int t = 0; t < 9; ++t) acc[co] += v[t] * w[t];
    }
  }

  __shared__ float red[4][18][64];
#pragma unroll
  for (int co = 0; co < 18; ++co) red[wave][co][lane] = acc[co];
  __syncthreads();
  for (int o = tid; o < 18 * 64; o += 256) {
    const int co = o >> 6, wo = o & 63;
    float s = red[0][co][wo] + red[1][co][wo] + red[2][co][wo] + red[3][co][wo];
    if (seg == 0) s += off_b[co];
    atomicAdd(&offs[((n * 18 + co) << 12) + (ho << 6) + wo], s);
  }
}

// ---------------------------------------------------------------------------
// K2: mask deform conv on depth + sigmoid. 256 blocks (n,ho), 512 thr = 8 waves.
// ---------------------------------------------------------------------------
__global__ __launch_bounds__(512) void k_mask_conv(
    const float* __restrict__ depth, const float* __restrict__ offs,
    const float* __restrict__ mask_w, const float* __restrict__ mask_b,
    float* __restrict__ mask)
{
  const int n  = blockIdx.x >> 6;
  const int ho = blockIdx.x & 63;
  const int tid  = threadIdx.x;
  const int lane = tid & 63;          // wo
  const int wave = tid >> 6;          // 0..7
  const int wo = lane;

  int i00[9], i01[9], i10[9], i11[9];
  float cw00[9], cw01[9], cw10[9], cw11[9];
  const float* op = offs + ((n * 18) << 12) + (ho << 6) + wo;
#pragma unroll
  for (int k = 0; k < 9; ++k) {
    const float dy = op[(2 * k) << 12];
    const float dx = op[(2 * k + 1) << 12];
    const float yy = (float)(ho - 1 + k / 3) + dy;
    const float xx = (float)(wo - 1 + k % 3) + dx;
    const float y0f = floorf(yy), x0f = floorf(xx);
    const float ly = yy - y0f, lx = xx - x0f;
    const int y0 = (int)y0f, x0 = (int)x0f;
    const int y0c = min(max(y0, 0), 63),     x0c = min(max(x0, 0), 63);
    const int y1c = min(max(y0 + 1, 0), 63), x1c = min(max(x0 + 1, 0), 63);
    const float fy0 = (y0 >= 0 && y0 < 64) ? 1.f : 0.f;
    const float fy1 = (y0 >= -1 && y0 < 63) ? 1.f : 0.f;
    const float fx0 = (x0 >= 0 && x0 < 64) ? 1.f : 0.f;
    const float fx1 = (x0 >= -1 && x0 < 63) ? 1.f : 0.f;
    i00[k] = (y0c << 6) + x0c;  i01[k] = (y0c << 6) + x1c;
    i10[k] = (y1c << 6) + x0c;  i11[k] = (y1c << 6) + x1c;
    cw00[k] = (1.f - ly) * (1.f - lx) * fy0 * fx0;
    cw01[k] = (1.f - ly) * lx * fy0 * fx1;
    cw10[k] = ly * (1.f - lx) * fy1 * fx0;
    cw11[k] = ly * lx * fy1 * fx1;
  }

  float acc[9];
#pragma unroll
  for (int i = 0; i < 9; ++i) acc[i] = 0.f;

  const int cbase = __builtin_amdgcn_readfirstlane(wave * 8);
  for (int cc = 0; cc < 8; ++cc) {
    const int c = cbase + cc;
    const float* p = depth + (((n << 6) + c) << 12);
    float val[9];
#pragma unroll
    for (int k = 0; k < 9; ++k) {
      val[k] = p[i00[k]] * cw00[k] + p[i01[k]] * cw01[k] +
               p[i10[k]] * cw10[k] + p[i11[k]] * cw11[k];
    }
    const float* wp = mask_w + c * 9;
#pragma unroll
    for (int co = 0; co < 9; ++co) {
#pragma unroll
      for (int k = 0; k < 9; ++k) acc[co] += val[k] * wp[co * 576 + k];
    }
  }

  __shared__ float red[8][9][64];
#pragma unroll
  for (int co = 0; co < 9; ++co) red[wave][co][lane] = acc[co];
  __syncthreads();
  for (int o = tid; o < 9 * 64; o += 512) {
    const int co = o >> 6, w2 = o & 63;
    float s = mask_b[co];
#pragma unroll
    for (int w = 0; w < 8; ++w) s += red[w][co][w2];
    mask[((n * 9 + co) << 12) + (ho << 6) + w2] = 1.f / (1.f + expf(-s));
  }
}

// ---------------------------------------------------------------------------
// K3: main modulated deform conv, bf16 MFMA GEMM, channel-major K.
// C[256co x 16384px] = Wbf[256 x 2304] * cols[2304 x px], k = c*9 + tap.
// Block: BN=64 px (one output row), BM=256, BK=64, 512 thr = 8 waves, grid 256.
// x gathered from an LDS strip ring (9 slots x 18 rows x 64 f32), staged with
// global_load_lds; rare global fallback for |dy|>8.
// ---------------------------------------------------------------------------
__device__ __forceinline__ void stage_channel(const float* src, float* dstb,
                                              int lane) {
  // copy 4608 B (18 rows x 256 B) global -> LDS, linear, lane-striped
  const char* s = (const char*)src + lane * 16;
  char* d = (char*)dstb;
#pragma unroll
  for (int j = 0; j < 4; ++j)
    __builtin_amdgcn_global_load_lds(
        (const __attribute__((address_space(1))) void*)(s + j * 1024),
        (__attribute__((address_space(3))) void*)(d + j * 1024), 16, 0, 0);
  if (lane < 32)
    __builtin_amdgcn_global_load_lds(
        (const __attribute__((address_space(1))) void*)(s + 4096),
        (__attribute__((address_space(3))) void*)(d + 4096), 16, 0, 0);
}

__global__ __launch_bounds__(512, 2) void k_deform_gemm(
    const float* __restrict__ x, const float* __restrict__ offs,
    const float* __restrict__ mask, const unsigned short* __restrict__ wbf,
    const float* __restrict__ bias, float* __restrict__ out)
{
  __shared__ float strip[9 * 1152];                    // 41472 B (9 ch slots)
  __shared__ __align__(16) unsigned short Bs[64][72];  // 9216 B (single buf)
  __shared__ float4 pwT[9][64];                        // 9216 B
  __shared__ int    piT[9][64];                        // 2304 B  -> 60.75 KB

  const int tid = threadIdx.x;
  // XCD swizzle: b&7 = XCD; each XCD owns a 32-row strip of one batch.
  const int b    = blockIdx.x;            // 256 blocks
  const int xcd  = b & 7, bslot = b >> 3; // bslot 0..31
  const int n    = xcd >> 1;
  const int ho   = ((xcd & 1) << 5) + bslot;      // 0..63
  const int pxb  = ho << 6;                       // px base within batch
  const int ylo  = min(max(ho - 8, 0), 46);       // strip rows [ylo, ylo+18)

  // phase 0: sampling params for 64 px x 9 taps (e = tap*64 + px)
  for (int e = tid; e < 576; e += 512) {
    const int tap = e >> 6, pl = e & 63;
    const int wo = pl;
    const float dy = offs[((n * 18 + 2 * tap) << 12) + pxb + pl];
    const float dx = offs[((n * 18 + 2 * tap + 1) << 12) + pxb + pl];
    const float m  = mask[((n * 9 + tap) << 12) + pxb + pl];
    const float yy = (float)(ho - 1 + tap / 3) + dy;
    const float xx = (float)(wo - 1 + tap % 3) + dx;
    const float y0f = floorf(yy), x0f = floorf(xx);
    const float ly = yy - y0f, lx = xx - x0f;
    const int y0 = (int)y0f, x0 = (int)x0f;
    const int y0c = min(max(y0, 0), 63);
    const int y1c = min(max(y0 + 1, 0), 63);
    const float fy0 = (y0 >= 0 && y0 < 64) ? 1.f : 0.f;
    const float fy1 = (y0 >= -1 && y0 < 63) ? 1.f : 0.f;
    // horizontal pair remap: contribution = wl*p[bx] + wr*p[bx+1], all
    // clamp/validity cases folded (bx<=62 -> pair never crosses the row).
    const int x0c = min(max(x0, 0), 63);
    const int x1c = min(max(x0 + 1, 0), 63);
    const int bx  = min(max(x0, 0), 62);
    const float vx0 = (x0 >= 0 && x0 < 64) ? 1.f : 0.f;
    const float vx1 = (x0 >= -1 && x0 < 63) ? 1.f : 0.f;
    const float wl = (1.f - lx) * vx0 * ((x0c == bx) ? 1.f : 0.f)
                   + lx * vx1 * ((x1c == bx) ? 1.f : 0.f);
    const float wr = (1.f - lx) * vx0 * ((x0c == bx + 1) ? 1.f : 0.f)
                   + lx * vx1 * ((x1c == bx + 1) ? 1.f : 0.f);
    const float a0 = (1.f - ly) * fy0 * m;
    const float a1 = ly * fy1 * m;
    pwT[tap][pl] = make_float4(wl * a0, wr * a0, wl * a1, wr * a1);
    piT[tap][pl] = bx | (y0c << 6) | (y1c << 12);   // 6+6+6 bits
  }

  const int pxl  = tid & 63;        // px within row (= lane)
  const int oct  = tid >> 6;        // wave id; k-octet of 8
  const int lane = tid & 63;
  const int mrow = lane & 15;
  const int koct = lane >> 4;       // 0..3 -> k-subgroup of 8
  const float* xn = x + ((long)(n << 8) << 12);

  // prologue: stage channels 0..7 (window of iter 0), one channel per wave
  stage_channel(xn + (oct << 12) + (ylo << 6), &strip[oct * 1152], lane);
  int c_staged = 8;
  __syncthreads();   // params + prologue strip visible

  // gather one k-octet (8 k) per lane into Bs
  auto gather = [&](int ic) {
    const int k0 = (ic << 6) + (oct << 3);
    int c   = (int)(((unsigned)k0 * 7282u) >> 16);    // k0/9
    int tap = k0 - 9 * c;
    int slt = c - 9 * (int)(((unsigned)c * 7282u) >> 16);  // c%9
    const char* pg = (const char*)xn + (c << 14);
    int soff = slt * 1152;
    __align__(16) unsigned short v[8];
#pragma unroll
    for (int j = 0; j < 8; ++j) {
      const float4 w = pwT[tap][pxl];
      const int pk = piT[tap][pxl];
      const int bx = pk & 63;
      const int ry0 = ((pk >> 6) & 63) - ylo;
      const int ry1 = ((pk >> 12) & 63) - ylo;
      float a0, a1, b0, b1;
      if ((unsigned)ry0 < 18u) {
        const float* s = &strip[soff + (ry0 << 6) + bx]; a0 = s[0]; a1 = s[1];
      } else {
        const float2_u t = *(const float2_u*)(pg + (((((pk >> 6) & 63) << 6) + bx) << 2));
        a0 = t.x; a1 = t.y;
      }
      if ((unsigned)ry1 < 18u) {
        const float* s = &strip[soff + (ry1 << 6) + bx]; b0 = s[0]; b1 = s[1];
      } else {
        const float2_u t = *(const float2_u*)(pg + (((((pk >> 12) & 63) << 6) + bx) << 2));
        b0 = t.x; b1 = t.y;
      }
      v[j] = f2bf(a0 * w.x + a1 * w.y + b0 * w.z + b1 * w.w);
      if (++tap == 9) { tap = 0; pg += 16384; if (++slt == 9) slt = 0; soff = slt * 1152; }
    }
    *(int4*)&Bs[pxl][oct << 3] = *(const int4*)v;
  };

  gather(0);
  __syncthreads();

  f32x4 acc[2][4];
#pragma unroll
  for (int mt = 0; mt < 2; ++mt)
#pragma unroll
    for (int nt = 0; nt < 4; ++nt)
#pragma unroll
      for (int r = 0; r < 4; ++r) acc[mt][nt][r] = 0.f;

  for (int ic = 0; ic < 36; ++ic) {
    // 1. stage next window's new channels (overlaps MFMA; drained at barrier)
    if (ic < 35) {
      const int c_end = (64 * ic + 127) / 9;          // c_hi(ic+1) <= 255
      const int cw = c_staged + oct;
      if (cw <= c_end) {
        const int slt = cw - 9 * (int)(((unsigned)cw * 7282u) >> 16);
        stage_channel(xn + (cw << 12) + (ylo << 6), &strip[slt * 1152], lane);
      }
      c_staged = c_end + 1;
    }

    // 2. A fragments (global, L2-hot) + MFMA on Bs (written last iter)
    const int kc = ic << 6;
    bf16x8 af[2][2];
#pragma unroll
    for (int mt = 0; mt < 2; ++mt)
#pragma unroll
      for (int ks = 0; ks < 2; ++ks) {
        const int row = (oct << 5) + (mt << 4) + mrow;
        const int col = kc + (ks << 5) + (koct << 3);
        af[mt][ks] = *(const bf16x8*)(wbf + row * 2304 + col);
      }
#pragma unroll
    for (int ks = 0; ks < 2; ++ks)
#pragma unroll
      for (int nt = 0; nt < 4; ++nt) {
        const bf16x8 bfr =
            *(const bf16x8*)&Bs[(nt << 4) + mrow][(ks << 5) + (koct << 3)];
        acc[0][nt] = __builtin_amdgcn_mfma_f32_16x16x32_bf16(af[0][ks], bfr,
                                                             acc[0][nt], 0, 0, 0);
        acc[1][nt] = __builtin_amdgcn_mfma_f32_16x16x32_bf16(af[1][ks], bfr,
                                                             acc[1][nt], 0, 0, 0);
      }

    __syncthreads();           // drains stage; Bs free for rewrite
    if (ic < 35) gather(ic + 1);
    __syncthreads();           // Bs ready for next MFMA; strip safe to restage
  }

  // epilogue: C/D layout col=lane&15 (px), row=(lane>>4)*4+r (co)
#pragma unroll
  for (int mt = 0; mt < 2; ++mt)
#pragma unroll
    for (int nt = 0; nt < 4; ++nt)
#pragma unroll
      for (int r = 0; r < 4; ++r) {
        const int co = (oct << 5) + (mt << 4) + ((lane >> 4) << 2) + r;
        const int pxg = pxb + (nt << 4) + (lane & 15);
        out[(((n << 8) + co) << 12) + pxg] = acc[mt][nt][r] + bias[co];
      }
}

// ---------------------------------------------------------------------------
extern "C" void kernel_launch(void* const* d_in, const int* in_sizes, int n_in,
                              void* d_out, int out_size, void* d_ws, size_t ws_size,
                              hipStream_t stream) {
  const float* x      = (const float*)d_in[0];
  const float* depth  = (const float*)d_in[1];
  const float* weight = (const float*)d_in[2];
  const float* bias   = (const float*)d_in[3];
  const float* off_w  = (const float*)d_in[4];
  const float* off_b  = (const float*)d_in[5];
  const float* mask_w = (const float*)d_in[6];
  const float* mask_b = (const float*)d_in[7];
  float* out = (float*)d_out;

  float* offs = (float*)d_ws;                       // 294912 floats
  float* mask = offs + 294912;                      // 147456 floats
  unsigned short* wbf = (unsigned short*)(mask + 147456);  // 589824 bf16

  hipMemsetAsync(offs, 0, 294912 * sizeof(float), stream);
  k_prep_weight<<<2304, 256, 0, stream>>>(weight, wbf);
  k_offset_conv<<<1024, 256, 0, stream>>>(x, depth, off_w, off_b, offs);
  k_mask_conv<<<256, 512, 0, stream>>>(depth, offs, mask_w, mask_b, mask);
  k_deform_gemm<<<256, 512, 0, stream>>>(x, offs, mask, wbf, bias, out);
}

// Round 3
// 264.214 us; speedup vs baseline: 1.1500x; 1.1500x over previous
//
#include <hip/hip_runtime.h>

// DepthDeformConvPack on MI355X — round 7: fix the r6 LDS gather properly.
// r6 post-mortem: 18-row strip => P(wave-read needs global fallback) ~44%
// (sigma_offset~2.7 -> ±8 rows is only 3-sigma; with 64 lanes nearly every
// wave diverged into BOTH paths), and the per-j if/else fenced all ILP
// (VGPR=64 -> serial chain, 10k cy/iter). Changes (K3 only):
//   (a) 32-row strip (±15 rows = 5.2 sigma): fallback probability ~1e-5 per
//       wave-gather (~10 events total run). Ring 9 x 8KB = 72KB, LDS 94.5KB.
//   (b) branchless gather: phase0 packs strip-relative byte addrs
//       (a0|a1<<13|bad<<26); main path = 8 ds_read_b32 -> 16 independent
//       ds_read_b64 + 8 ds_read_b128 -> fma/cvt -> ds_write_b128. Bad lanes
//       repaired in a __builtin_expect cold block via exact global loads.
//   (c) A-fragment register prefetch (af(ic+1) issued during iter ic) hides
//       the ~300cy L2 latency previously exposed every iteration.

typedef __bf16 bf16x8 __attribute__((ext_vector_type(8)));
typedef float f32x4 __attribute__((ext_vector_type(4)));
typedef float float2_u __attribute__((ext_vector_type(2), aligned(4)));

__device__ __forceinline__ unsigned short f2bf(float f) {
  unsigned b = __float_as_uint(f);
  return (unsigned short)((b + 0x7fffu + ((b >> 16) & 1u)) >> 16);
}

// ---------------------------------------------------------------------------
// K0: weight fp32 -> bf16, natural layout (k = c*9+tap is already channel-major)
// ---------------------------------------------------------------------------
__global__ __launch_bounds__(256) void k_prep_weight(
    const float* __restrict__ w, unsigned short* __restrict__ wbf)
{
  const int i = blockIdx.x * 256 + threadIdx.x;   // grid 2304 -> 589824
  wbf[i] = f2bf(w[i]);
}

// ---------------------------------------------------------------------------
// K1: offset conv. grid = 4 ch-segments x (n,ho)=256 -> 1024 blocks, 256 thr.
// ---------------------------------------------------------------------------
__global__ __launch_bounds__(256) void k_offset_conv(
    const float* __restrict__ x, const float* __restrict__ depth,
    const float* __restrict__ off_w, const float* __restrict__ off_b,
    float* __restrict__ offs)
{
  const int seg = blockIdx.x >> 8;        // 0..3
  const int nh  = blockIdx.x & 255;
  const int n = nh >> 6, ho = nh & 63;
  const int tid = threadIdx.x;
  const int lane = tid & 63;              // == wo
  const int wave = tid >> 6;

  float acc[18];
#pragma unroll
  for (int i = 0; i < 18; ++i) acc[i] = 0.f;

  const int c0 = __builtin_amdgcn_readfirstlane(seg * 80 + wave * 20);

  for (int ci = 0; ci < 20; ++ci) {
    const int c = c0 + ci;
    const float* p = (c < 256) ? (x + (((n << 8) + c) << 12))
                               : (depth + (((n << 6) + (c - 256)) << 12));
    const float v0 = (ho > 0)  ? p[((ho - 1) << 6) + lane] : 0.f;
    const float v1 =             p[( ho      << 6) + lane];
    const float v2 = (ho < 63) ? p[((ho + 1) << 6) + lane] : 0.f;

    float v[9];
#pragma unroll
    for (int ky = 0; ky < 3; ++ky) {
      const float r = (ky == 0) ? v0 : ((ky == 1) ? v1 : v2);
#pragma unroll
      for (int kx = 0; kx < 3; ++kx) {
        const int src = lane + kx - 1;
        const float s = __shfl(r, src & 63);
        v[ky * 3 + kx] = (src >= 0 && src < 64) ? s : 0.f;
      }
    }
    const float* wp = off_w + c * 9;   // wave-uniform address
#pragma unroll
    for (int co = 0; co < 18; ++co) {
      const float* w = wp + co * 2880;
#pragma unroll
      for (int t = 0; t < 9; ++t) acc[co] += v[t] * w[t];
    }
  }

  __shared__ float red[4][18][64];
#pragma unroll
  for (int co = 0; co < 18; ++co) red[wave][co][lane] = acc[co];
  __syncthreads();
  for (int o = tid; o < 18 * 64; o += 256) {
    const int co = o >> 6, wo = o & 63;
    float s = red[0][co][wo] + red[1][co][wo] + red[2][co][wo] + red[3][co][wo];
    if (seg == 0) s += off_b[co];
    atomicAdd(&offs[((n * 18 + co) << 12) + (ho << 6) + wo], s);
  }
}

// ---------------------------------------------------------------------------
// K2: mask deform conv on depth + sigmoid. 256 blocks (n,ho), 512 thr = 8 waves.
// ---------------------------------------------------------------------------
__global__ __launch_bounds__(512) void k_mask_conv(
    const float* __restrict__ depth, const float* __restrict__ offs,
    const float* __restrict__ mask_w, const float* __restrict__ mask_b,
    float* __restrict__ mask)
{
  const int n  = blockIdx.x >> 6;
  const int ho = blockIdx.x & 63;
  const int tid  = threadIdx.x;
  const int lane = tid & 63;          // wo
  const int wave = tid >> 6;          // 0..7
  const int wo = lane;

  int i00[9], i01[9], i10[9], i11[9];
  float cw00[9], cw01[9], cw10[9], cw11[9];
  const float* op = offs + ((n * 18) << 12) + (ho << 6) + wo;
#pragma unroll
  for (int k = 0; k < 9; ++k) {
    const float dy = op[(2 * k) << 12];
    const float dx = op[(2 * k + 1) << 12];
    const float yy = (float)(ho - 1 + k / 3) + dy;
    const float xx = (float)(wo - 1 + k % 3) + dx;
    const float y0f = floorf(yy), x0f = floorf(xx);
    const float ly = yy - y0f, lx = xx - x0f;
    const int y0 = (int)y0f, x0 = (int)x0f;
    const int y0c = min(max(y0, 0), 63),     x0c = min(max(x0, 0), 63);
    const int y1c = min(max(y0 + 1, 0), 63), x1c = min(max(x0 + 1, 0), 63);
    const float fy0 = (y0 >= 0 && y0 < 64) ? 1.f : 0.f;
    const float fy1 = (y0 >= -1 && y0 < 63) ? 1.f : 0.f;
    const float fx0 = (x0 >= 0 && x0 < 64) ? 1.f : 0.f;
    const float fx1 = (x0 >= -1 && x0 < 63) ? 1.f : 0.f;
    i00[k] = (y0c << 6) + x0c;  i01[k] = (y0c << 6) + x1c;
    i10[k] = (y1c << 6) + x0c;  i11[k] = (y1c << 6) + x1c;
    cw00[k] = (1.f - ly) * (1.f - lx) * fy0 * fx0;
    cw01[k] = (1.f - ly) * lx * fy0 * fx1;
    cw10[k] = ly * (1.f - lx) * fy1 * fx0;
    cw11[k] = ly * lx * fy1 * fx1;
  }

  float acc[9];
#pragma unroll
  for (int i = 0; i < 9; ++i) acc[i] = 0.f;

  const int cbase = __builtin_amdgcn_readfirstlane(wave * 8);
  for (int cc = 0; cc < 8; ++cc) {
    const int c = cbase + cc;
    const float* p = depth + (((n << 6) + c) << 12);
    float val[9];
#pragma unroll
    for (int k = 0; k < 9; ++k) {
      val[k] = p[i00[k]] * cw00[k] + p[i01[k]] * cw01[k] +
               p[i10[k]] * cw10[k] + p[i11[k]] * cw11[k];
    }
    const float* wp = mask_w + c * 9;
#pragma unroll
    for (int co = 0; co < 9; ++co) {
#pragma unroll
      for (int k = 0; k < 9; ++k) acc[co] += val[k] * wp[co * 576 + k];
    }
  }

  __shared__ float red[8][9][64];
#pragma unroll
  for (int co = 0; co < 9; ++co) red[wave][co][lane] = acc[co];
  __syncthreads();
  for (int o = tid; o < 9 * 64; o += 512) {
    const int co = o >> 6, w2 = o & 63;
    float s = mask_b[co];
#pragma unroll
    for (int w = 0; w < 8; ++w) s += red[w][co][w2];
    mask[((n * 9 + co) << 12) + (ho << 6) + w2] = 1.f / (1.f + expf(-s));
  }
}

// ---------------------------------------------------------------------------
// K3: main modulated deform conv, bf16 MFMA GEMM, channel-major K.
// C[256co x 16384px] = Wbf[256 x 2304] * cols[2304 x px], k = c*9 + tap.
// Block: BN=64 px (one output row), BM=256, BK=64, 512 thr = 8 waves, grid 256.
// x gathered from a 9-slot LDS strip ring (32 rows x 64 f32 per channel).
// ---------------------------------------------------------------------------
__device__ __forceinline__ void stage_channel8k(const float* src, float* dstb,
                                                int lane) {
  // copy 8192 B (32 rows x 256 B) global -> LDS, linear, lane-striped
  const char* s = (const char*)src + lane * 16;
  char* d = (char*)dstb;
#pragma unroll
  for (int j = 0; j < 8; ++j)
    __builtin_amdgcn_global_load_lds(
        (const __attribute__((address_space(1))) void*)(s + j * 1024),
        (__attribute__((address_space(3))) void*)(d + j * 1024), 16, 0, 0);
}

__global__ __launch_bounds__(512, 2) void k_deform_gemm(
    const float* __restrict__ x, const float* __restrict__ offs,
    const float* __restrict__ mask, const unsigned short* __restrict__ wbf,
    const float* __restrict__ bias, float* __restrict__ out)
{
  __shared__ float strip[9 * 2048];                    // 73728 B (9 ch slots)
  __shared__ __align__(16) unsigned short Bs[64][72];  // 9216 B
  __shared__ float4 pwT[9][64];                        // 9216 B
  __shared__ int    piT[9][64];                        // 2304 B (strip-packed)
  __shared__ int    piF[9][64];                        // 2304 B (fallback)
                                                       // total 96768 B

  const int tid = threadIdx.x;
  // XCD swizzle: b&7 = XCD; each XCD owns a 32-row strip of one batch.
  const int b    = blockIdx.x;            // 256 blocks
  const int xcd  = b & 7, bslot = b >> 3; // bslot 0..31
  const int n    = xcd >> 1;
  const int ho   = ((xcd & 1) << 5) + bslot;      // 0..63
  const int pxb  = ho << 6;                       // px base within batch
  const int ylo  = min(max(ho - 15, 0), 32);      // strip rows [ylo, ylo+32)

  // phase 0: sampling params for 64 px x 9 taps (e = tap*64 + px)
  for (int e = tid; e < 576; e += 512) {
    const int tap = e >> 6, pl = e & 63;
    const int wo = pl;
    const float dy = offs[((n * 18 + 2 * tap) << 12) + pxb + pl];
    const float dx = offs[((n * 18 + 2 * tap + 1) << 12) + pxb + pl];
    const float m  = mask[((n * 9 + tap) << 12) + pxb + pl];
    const float yy = (float)(ho - 1 + tap / 3) + dy;
    const float xx = (float)(wo - 1 + tap % 3) + dx;
    const float y0f = floorf(yy), x0f = floorf(xx);
    const float ly = yy - y0f, lx = xx - x0f;
    const int y0 = (int)y0f, x0 = (int)x0f;
    const int y0c = min(max(y0, 0), 63);
    const int y1c = min(max(y0 + 1, 0), 63);
    const float fy0 = (y0 >= 0 && y0 < 64) ? 1.f : 0.f;
    const float fy1 = (y0 >= -1 && y0 < 63) ? 1.f : 0.f;
    // horizontal pair remap: contribution = wl*p[bx] + wr*p[bx+1], all
    // clamp/validity cases folded (bx<=62 -> pair never crosses the row).
    const int x0c = min(max(x0, 0), 63);
    const int x1c = min(max(x0 + 1, 0), 63);
    const int bx  = min(max(x0, 0), 62);
    const float vx0 = (x0 >= 0 && x0 < 64) ? 1.f : 0.f;
    const float vx1 = (x0 >= -1 && x0 < 63) ? 1.f : 0.f;
    const float wl = (1.f - lx) * vx0 * ((x0c == bx) ? 1.f : 0.f)
                   + lx * vx1 * ((x1c == bx) ? 1.f : 0.f);
    const float wr = (1.f - lx) * vx0 * ((x0c == bx + 1) ? 1.f : 0.f)
                   + lx * vx1 * ((x1c == bx + 1) ? 1.f : 0.f);
    const float a0 = (1.f - ly) * fy0 * m;
    const float a1 = ly * fy1 * m;
    pwT[tap][pl] = make_float4(wl * a0, wr * a0, wl * a1, wr * a1);
    // strip-relative packed byte addrs + bad flag
    const int ry0 = y0c - ylo, ry1 = y1c - ylo;
    const int ry0c = min(max(ry0, 0), 31), ry1c = min(max(ry1, 0), 31);
    const int bad = ((ry0 != ry0c) || (ry1 != ry1c)) ? 1 : 0;
    const int ad0 = (ry0c << 8) | (bx << 2);      // < 8192
    const int ad1 = (ry1c << 8) | (bx << 2);
    piT[tap][pl] = ad0 | (ad1 << 13) | (bad << 26);
    piF[tap][pl] = bx | (y0c << 6) | (y1c << 12); // exact fallback coords
  }

  const int pxl  = tid & 63;        // px within row (= lane)
  const int oct  = tid >> 6;        // wave id; k-octet of 8
  const int lane = tid & 63;
  const int mrow = lane & 15;
  const int koct = lane >> 4;       // 0..3 -> k-subgroup of 8
  const float* xn = x + ((long)(n << 8) << 12);
  const char* xnc = (const char*)xn;
  const char* stripb = (const char*)strip;

  // prologue: stage channels 0..7 (window of iter 0), one channel per wave
  stage_channel8k(xn + (oct << 12) + (ylo << 6), &strip[oct * 2048], lane);
  int c_staged = 8;
  __syncthreads();   // params + prologue strip visible

  // branchless gather of one k-octet (8 k) per lane into Bs
  auto gather = [&](int ic) {
    const int k0 = (ic << 6) + (oct << 3);
    int tp[8], sof[8];
#pragma unroll
    for (int j = 0; j < 8; ++j) {             // per-j channel math (no chain)
      const int k = k0 + j;
      const int c = (int)(((unsigned)k * 7282u) >> 16);       // k/9
      tp[j] = k - 9 * c;
      const int s9 = (int)(((unsigned)c * 7282u) >> 16);      // c/9
      sof[j] = (c - 9 * s9) << 13;            // slot byte offset (8 KB slots)
    }
    int pk[8];
#pragma unroll
    for (int j = 0; j < 8; ++j) pk[j] = piT[tp[j]][pxl];      // 8x ds_read_b32
    float4 w[8];
#pragma unroll
    for (int j = 0; j < 8; ++j) w[j] = pwT[tp[j]][pxl];       // 8x ds_read_b128
    float2_u A[8], B[8];
#pragma unroll
    for (int j = 0; j < 8; ++j) {             // 16 independent ds_read_b64
      A[j] = *(const float2_u*)(stripb + sof[j] + (pk[j] & 8191));
      B[j] = *(const float2_u*)(stripb + sof[j] + ((pk[j] >> 13) & 8191));
    }
    int badm = 0;
    __align__(16) unsigned short v[8];
#pragma unroll
    for (int j = 0; j < 8; ++j) {
      v[j] = f2bf(A[j].x * w[j].x + A[j].y * w[j].y +
                  B[j].x * w[j].z + B[j].y * w[j].w);
      badm |= (pk[j] >> 26) << j;
    }
    if (__builtin_expect(badm != 0, 0)) {     // ~1e-5 per wave-gather
#pragma unroll
      for (int j = 0; j < 8; ++j) if (badm & (1 << j)) {
        const int k = k0 + j;
        const int c = (int)(((unsigned)k * 7282u) >> 16);
        const char* pg = xnc + ((long)c << 14);
        const int pf = piF[tp[j]][pxl];
        const int bx = pf & 63, y0c = (pf >> 6) & 63, y1c = (pf >> 12) & 63;
        const float2_u Ag = *(const float2_u*)(pg + ((((y0c << 6) + bx)) << 2));
        const float2_u Bg = *(const float2_u*)(pg + ((((y1c << 6) + bx)) << 2));
        v[j] = f2bf(Ag.x * w[j].x + Ag.y * w[j].y +
                    Bg.x * w[j].z + Bg.y * w[j].w);
      }
    }
    *(int4*)&Bs[pxl][oct << 3] = *(const int4*)v;
  };

  // A-fragment prefetch registers for iter 0
  bf16x8 afc[2][2];
#pragma unroll
  for (int mt = 0; mt < 2; ++mt)
#pragma unroll
    for (int ks = 0; ks < 2; ++ks) {
      const int row = (oct << 5) + (mt << 4) + mrow;
      const int col = (ks << 5) + (koct << 3);
      afc[mt][ks] = *(const bf16x8*)(wbf + row * 2304 + col);
    }

  gather(0);
  __syncthreads();

  f32x4 acc[2][4];
#pragma unroll
  for (int mt = 0; mt < 2; ++mt)
#pragma unroll
    for (int nt = 0; nt < 4; ++nt)
#pragma unroll
      for (int r = 0; r < 4; ++r) acc[mt][nt][r] = 0.f;

  for (int ic = 0; ic < 36; ++ic) {
    // phase 1: stage next window's channels + prefetch af(ic+1) + MFMA(ic)
    if (ic < 35) {
      const int c_end = (64 * ic + 127) / 9;          // c_hi(ic+1) <= 255
      const int cw = c_staged + oct;
      if (cw <= c_end) {
        const int slt = cw - 9 * (int)(((unsigned)cw * 7282u) >> 16);
        stage_channel8k(xn + (cw << 12) + (ylo << 6), &strip[slt * 2048], lane);
      }
      c_staged = c_end + 1;
    }

    bf16x8 afn[2][2];
    if (ic < 35) {
      const int kc = (ic + 1) << 6;
#pragma unroll
      for (int mt = 0; mt < 2; ++mt)
#pragma unroll
        for (int ks = 0; ks < 2; ++ks) {
          const int row = (oct << 5) + (mt << 4) + mrow;
          const int col = kc + (ks << 5) + (koct << 3);
          afn[mt][ks] = *(const bf16x8*)(wbf + row * 2304 + col);
        }
    }

#pragma unroll
    for (int ks = 0; ks < 2; ++ks)
#pragma unroll
      for (int nt = 0; nt < 4; ++nt) {
        const bf16x8 bfr =
            *(const bf16x8*)&Bs[(nt << 4) + mrow][(ks << 5) + (koct << 3)];
        acc[0][nt] = __builtin_amdgcn_mfma_f32_16x16x32_bf16(afc[0][ks], bfr,
                                                             acc[0][nt], 0, 0, 0);
        acc[1][nt] = __builtin_amdgcn_mfma_f32_16x16x32_bf16(afc[1][ks], bfr,
                                                             acc[1][nt], 0, 0, 0);
      }

    __syncthreads();           // drains stage; Bs free for rewrite
    if (ic < 35) gather(ic + 1);
    __syncthreads();           // Bs ready for next MFMA; strip safe to restage

#pragma unroll
    for (int mt = 0; mt < 2; ++mt)
#pragma unroll
      for (int ks = 0; ks < 2; ++ks) afc[mt][ks] = afn[mt][ks];
  }

  // epilogue: C/D layout col=lane&15 (px), row=(lane>>4)*4+r (co)
#pragma unroll
  for (int mt = 0; mt < 2; ++mt)
#pragma unroll
    for (int nt = 0; nt < 4; ++nt)
#pragma unroll
      for (int r = 0; r < 4; ++r) {
        const int co = (oct << 5) + (mt << 4) + ((lane >> 4) << 2) + r;
        const int pxg = pxb + (nt << 4) + (lane & 15);
        out[(((n << 8) + co) << 12) + pxg] = acc[mt][nt][r] + bias[co];
      }
}

// ---------------------------------------------------------------------------
extern "C" void kernel_launch(void* const* d_in, const int* in_sizes, int n_in,
                              void* d_out, int out_size, void* d_ws, size_t ws_size,
                              hipStream_t stream) {
  const float* x      = (const float*)d_in[0];
  const float* depth  = (const float*)d_in[1];
  const float* weight = (const float*)d_in[2];
  const float* bias   = (const float*)d_in[3];
  const float* off_w  = (const float*)d_in[4];
  const float* off_b  = (const float*)d_in[5];
  const float* mask_w = (const float*)d_in[6];
  const float* mask_b = (const float*)d_in[7];
  float* out = (float*)d_out;

  float* offs = (float*)d_ws;                       // 294912 floats
  float* mask = offs + 294912;                      // 147456 floats
  unsigned short* wbf = (unsigned short*)(mask + 147456);  // 589824 bf16

  hipMemsetAsync(offs, 0, 294912 * sizeof(float), stream);
  k_prep_weight<<<2304, 256, 0, stream>>>(weight, wbf);
  k_offset_conv<<<1024, 256, 0, stream>>>(x, depth, off_w, off_b, offs);
  k_mask_conv<<<256, 512, 0, stream>>>(depth, offs, mask_w, mask_b, mask);
  k_deform_gemm<<<256, 512, 0, stream>>>(x, offs, mask, wbf, bias, out);
}